// Round 1
// 160.725 us; speedup vs baseline: 1.0345x; 1.0345x over previous
//
#include <hip/hip_runtime.h>
#include <hip/hip_bf16.h>

#define NROWS 65536
#define DIM   256
#define NCLS  1000
#define CPAD  1024

typedef __attribute__((ext_vector_type(8))) short bf16x8;   // 8 bf16 = 4 VGPR
typedef __attribute__((ext_vector_type(4))) float f32x4;    // MFMA C/D

// RTNE float -> bf16 bit pattern (finite inputs only)
__device__ inline unsigned short f2bf(float x) {
    unsigned int u = __builtin_bit_cast(unsigned int, x);
    unsigned int lsb = (u >> 16) & 1u;
    u += 0x7fffu + lsb;
    return (unsigned short)(u >> 16);
}

__device__ inline float bf2f(unsigned short u) {
    unsigned int v = ((unsigned int)u) << 16;
    return __builtin_bit_cast(float, v);
}

// async global->LDS, 16 B per lane, dst = wave-uniform base + lane*16
__device__ inline void gload_lds16(const void* g, void* l) {
    __builtin_amdgcn_global_load_lds(
        (const __attribute__((address_space(1))) unsigned int*)g,
        (__attribute__((address_space(3))) unsigned int*)l, 16, 0, 0);
}

// K1: 8 rows per wave, 4-row batched pipeline (R9). Also zeroes the
// sums/counts/acc/done scratch (stream-ordered before K2 needs it).
__global__ __launch_bounds__(256) void k_norm_acc(
    const float* __restrict__ emb, unsigned short* __restrict__ e,
    float* __restrict__ sums, unsigned int* __restrict__ counts,
    float* __restrict__ acc, unsigned int* __restrict__ done)
{
    const int tid = threadIdx.x;
    const int bid = blockIdx.x;
    // zero scratch: 2048 blocks x 128 floats = CPAD*DIM sums
    if (tid < 128) sums[bid * 128 + tid] = 0.0f;
    if (bid < 16 && tid < 64) counts[bid * 64 + tid] = 0u;   // 1024 counts
    if (bid == 0 && tid == 0) { *acc = 0.0f; *done = 0u; }

    const int wave = tid >> 6, lane = tid & 63;
    const int w = bid * 4 + wave;                 // 8192 waves, 8 rows each

    #pragma unroll
    for (int i = 0; i < 2; ++i) {
        const int rbase = w * 8 + i * 4;
        float4 v[4];
        #pragma unroll
        for (int r = 0; r < 4; ++r)
            v[r] = ((const float4*)(emb + (size_t)(rbase + r) * DIM))[lane];
        float ss[4];
        #pragma unroll
        for (int r = 0; r < 4; ++r)
            ss[r] = v[r].x*v[r].x + v[r].y*v[r].y + v[r].z*v[r].z + v[r].w*v[r].w;
        #pragma unroll
        for (int off = 1; off < 64; off <<= 1) {
            #pragma unroll
            for (int r = 0; r < 4; ++r) ss[r] += __shfl_xor(ss[r], off);
        }
        #pragma unroll
        for (int r = 0; r < 4; ++r) {
            float inv = 1.0f / fmaxf(sqrtf(ss[r]), 1e-12f);
            ushort4 u;
            u.x = f2bf(v[r].x * inv); u.y = f2bf(v[r].y * inv);
            u.z = f2bf(v[r].z * inv); u.w = f2bf(v[r].w * inv);
            ((ushort4*)(e + (size_t)(rbase + r) * DIM))[lane] = u;
        }
    }
}

// K2: partial class sums, 2000 blocks = 1000 classes x 2 row-halves
// (~31 waves/CU: the gather while-loops are latency-bound — R9 proved TLP
// is what they need). Ballot-scan half the labels, wave-cooperative row
// gathers, flush via one fp32 global atomic per dim + one counts atomic.
__global__ __launch_bounds__(256) void k_gather_partial(
    const unsigned short* __restrict__ e, const int* __restrict__ labels,
    float* __restrict__ sums, unsigned int* __restrict__ counts)
{
    const int c   = blockIdx.x >> 1;       // 0..999
    const int h   = blockIdx.x & 1;        // row half
    const int tid = threadIdx.x;
    const int wave = tid >> 6, lane = tid & 63;

    __shared__ float part[4][DIM];
    __shared__ unsigned int cnt_s[4];

    const int base = h * (NROWS / 2);
    float a0 = 0.f, a1 = 0.f, a2 = 0.f, a3 = 0.f;
    unsigned int cnt = 0;

    for (int it = 0; it < (NROWS / 2) / 256 / 8; ++it) {   // 16 iterations
        int lb[8];
        #pragma unroll
        for (int u = 0; u < 8; ++u)
            lb[u] = labels[base + (it * 8 + u) * 256 + wave * 64 + lane];
        #pragma unroll
        for (int u = 0; u < 8; ++u) {
            unsigned long long m = __ballot(lb[u] == c);
            cnt += (unsigned int)__popcll(m);
            int rb = base + (it * 8 + u) * 256 + wave * 64;
            while (m) {
                int b = __ffsll((long long)m) - 1;  m &= m - 1;
                ushort4 v = ((const ushort4*)(e + (size_t)(rb + b) * DIM))[lane];
                a0 += bf2f(v.x); a1 += bf2f(v.y); a2 += bf2f(v.z); a3 += bf2f(v.w);
            }
        }
    }
    ((float4*)part[wave])[lane] = make_float4(a0, a1, a2, a3);
    if (lane == 0) cnt_s[wave] = cnt;
    __syncthreads();

    float s = part[0][tid] + part[1][tid] + part[2][tid] + part[3][tid];
    atomicAdd(&sums[(size_t)c * DIM + tid], s);
    if (tid == 0)
        atomicAdd(&counts[c], cnt_s[0] + cnt_s[1] + cnt_s[2] + cnt_s[3]);
}

// K3: one wave per class (all CPAD): center = sum/max(cnt,1), fold
// 1/max(||c||,1e-8), store bf16. Phantoms: sums=0,counts=0 -> cs=0.
__global__ __launch_bounds__(256) void k_centers(
    const float* __restrict__ sums, const unsigned int* __restrict__ counts,
    unsigned short* __restrict__ cs)
{
    int gid  = blockIdx.x * 256 + threadIdx.x;
    int c    = gid >> 6;          // wave-uniform
    int lane = gid & 63;
    float4 v = ((const float4*)(sums + (size_t)c * DIM))[lane];
    float ic = 1.0f / fmaxf((float)counts[c], 1.0f);
    v.x *= ic; v.y *= ic; v.z *= ic; v.w *= ic;
    float ss = v.x*v.x + v.y*v.y + v.z*v.z + v.w*v.w;
    #pragma unroll
    for (int off = 1; off < 64; off <<= 1) ss += __shfl_xor(ss, off);
    float sc = 1.0f / fmaxf(sqrtf(ss), 1e-8f);
    ushort4 u;
    u.x = f2bf(v.x * sc); u.y = f2bf(v.y * sc);
    u.z = f2bf(v.z * sc); u.w = f2bf(v.w * sc);
    ((ushort4*)(cs + (size_t)c * DIM))[lane] = u;
}

// K4 v2 (R10): bf16 MFMA GEMM-BT + fused loss + fused finalization.
// Changes vs R9 (which stalled at MfmaUtil 24% on the per-step
// vmcnt(0)+lgkmcnt(0) barrier drain):
//  - A entirely in registers: af[kc][mi][kk], 16 bf16x8 = 64 VGPR, loaded
//    once in the preamble. Removes all A ds_reads and the 32 KB a_s.
//  - Wave grid 4x1 (each wave: 32 rows x full 128-class tile) to keep
//    A-regs at 64 and total VGPR < 256. All reg indices compile-time.
//  - B: 4-deep LDS rotation (4 x 16 KB = 64 KB), staged 3 steps ahead;
//    buffer for step t is b_s[t&3]; stage target (t+3)&3 is compile-time
//    per unrolled kc. Tail stages wrap source row with &(CPAD-1): junk
//    lands in buffers never read again.
//  - T3/T4: counted "s_waitcnt vmcnt(8)" + raw s_barrier per step. One
//    barrier per step is sufficient: a wave passing barrier(t) has
//    finished its reads(t-1) (compiler lgkmcnt before MFMA(t-1) precedes
//    the barrier in program order), so stage(t+3) -> buf[(t-1)&3] issued
//    after the barrier cannot race; vmcnt(8) before the barrier proves
//    each wave's step-t glds landed before anyone reads buf[t&3].
//    sched_barrier(0) brackets pin MFMAs/reads inside their step.
//  - No other vmem ops inside the t-loop (labels/A loaded in preamble,
//    drained by the prologue __syncthreads) so vmcnt counting is exact.
#define TMB 128
#define TCB 128

__global__ __launch_bounds__(256, 2) void k_loss_mfma(
    const unsigned short* __restrict__ e, const unsigned short* __restrict__ cs,
    const int* __restrict__ labels, float* __restrict__ acc,
    unsigned int* __restrict__ done, float* __restrict__ out)
{
    __shared__ __align__(16) unsigned short b_s[4][TCB * 64];  // 64 KB
    __shared__ float red_s[4];

    const int tid  = threadIdx.x;
    const int row0 = blockIdx.x * TMB;
    const int wave = tid >> 6, lane = tid & 63;
    const int l16 = lane & 15, q = lane >> 4;
    const int st_r = lane >> 3;                // staging row within 8-row chunk
    const int st_s = (lane & 7) ^ st_r;        // XOR-swizzled source slice

    // labels for this lane's 8 output rows (C/D row = q*4 + rg)
    int labv[8];
    #pragma unroll
    for (int mi = 0; mi < 2; ++mi)
        #pragma unroll
        for (int rg = 0; rg < 4; ++rg)
            labv[mi * 4 + rg] = labels[row0 + wave*32 + mi*16 + q*4 + rg];

    // A fragments in registers, all indices compile-time (R7 lesson)
    bf16x8 af[4][2][2];
    #pragma unroll
    for (int mi = 0; mi < 2; ++mi) {
        const unsigned short* pa =
            e + (size_t)(row0 + wave*32 + mi*16 + l16) * DIM + q * 8;
        #pragma unroll
        for (int kc = 0; kc < 4; ++kc)
            #pragma unroll
            for (int kk = 0; kk < 2; ++kk)
                af[kc][mi][kk] = *(const bf16x8*)(pa + kc*64 + kk*32);
    }

    // prologue: stage steps (0,0)->buf0 (0,1)->buf1 (0,2)->buf2
    #pragma unroll
    for (int pt = 0; pt < 3; ++pt)
        #pragma unroll
        for (int ch = 0; ch < 4; ++ch) {
            int chunk = wave * 4 + ch;
            gload_lds16(&cs[(size_t)(chunk*8 + st_r) * DIM + pt*64 + st_s*8],
                        &b_s[pt][chunk * 512]);
        }
    __syncthreads();   // full drain: af/labv loads + prologue stages done

    float la_bulk = 0.0f, la_corr = 0.0f;
    const float KN = 1.0f / 999.0f;

    for (int cb = 0; cb < CPAD / TCB; ++cb) {
        f32x4 accf[2][8];
        #pragma unroll
        for (int mi = 0; mi < 2; ++mi)
            #pragma unroll
            for (int ni = 0; ni < 8; ++ni)
                accf[mi][ni] = (f32x4){0.f, 0.f, 0.f, 0.f};

        #pragma unroll
        for (int kc = 0; kc < 4; ++kc) {
            // step t = cb*4 + kc, reads b_s[kc] (staged 3 steps ago)
            __builtin_amdgcn_sched_barrier(0);
            // own glds for step t done; <=8 younger (t+1,t+2) may remain
            asm volatile("s_waitcnt vmcnt(8)" ::: "memory");
            __builtin_amdgcn_s_barrier();
            __builtin_amdgcn_sched_barrier(0);

            {   // stage step t+3 into b_s[(t+3)&3]
                const int t2  = cb * 4 + kc + 3;
                const int cb2 = t2 >> 2, kc2 = t2 & 3;   // kc2 == dest buf
                #pragma unroll
                for (int ch = 0; ch < 4; ++ch) {
                    int chunk = wave * 4 + ch;
                    int crow  = (cb2 * TCB + chunk * 8 + st_r) & (CPAD - 1);
                    gload_lds16(&cs[(size_t)crow * DIM + kc2*64 + st_s*8],
                                &b_s[kc2][chunk * 512]);
                }
            }

            #pragma unroll
            for (int kk = 0; kk < 2; ++kk) {
                bf16x8 bfr[8];
                #pragma unroll
                for (int ni = 0; ni < 8; ++ni) {
                    int rowB = ni * 16 + l16;
                    bfr[ni] = *(const bf16x8*)&b_s[kc][
                        rowB * 64 + (((kk*4 + q) ^ (rowB & 7)) * 8)];
                }
                #pragma unroll
                for (int mi = 0; mi < 2; ++mi)
                    #pragma unroll
                    for (int ni = 0; ni < 8; ++ni)
                        accf[mi][ni] = __builtin_amdgcn_mfma_f32_16x16x32_bf16(
                            af[kc][mi][kk], bfr[ni], accf[mi][ni], 0, 0, 0);
            }
        }

        // epilogue for this class tile: C/D col = cb*128 + ni*16 + l16,
        // row = wave*32 + mi*16 + q*4 + rg. Register-only (no vmem/LDS).
        #pragma unroll
        for (int mi = 0; mi < 2; ++mi)
            #pragma unroll
            for (int rg = 0; rg < 4; ++rg) {
                #pragma unroll
                for (int ni = 0; ni < 8; ++ni) {
                    float t = 1.0f - accf[mi][ni][rg];
                    la_bulk += t * t;
                }
                int lr = labv[mi*4 + rg] - cb*TCB - l16;
                if ((lr & ~112) == 0) {        // lr in {0,16,...,112}
                    int nih = lr >> 4;
                    float sv = (nih & 4)
                        ? ((nih & 2) ? ((nih & 1) ? accf[mi][7][rg] : accf[mi][6][rg])
                                     : ((nih & 1) ? accf[mi][5][rg] : accf[mi][4][rg]))
                        : ((nih & 2) ? ((nih & 1) ? accf[mi][3][rg] : accf[mi][2][rg])
                                     : ((nih & 1) ? accf[mi][1][rg] : accf[mi][0][rg]));
                    float t = 1.0f - sv;
                    la_corr += t * t;
                }
            }
    }

    // block reduction + fused finalization via atomic ticket
    float la = la_bulk * KN + la_corr * (1.0f - KN);
    #pragma unroll
    for (int off = 32; off >= 1; off >>= 1) la += __shfl_xor(la, off);
    if (lane == 0) red_s[wave] = la;
    __syncthreads();
    if (tid == 0) {
        atomicAdd(acc, red_s[0] + red_s[1] + red_s[2] + red_s[3]);
        __threadfence();
        unsigned int t = atomicAdd(done, 1u);
        if (t == (unsigned int)(NROWS / TMB) - 1u) {
            float v = atomicAdd(acc, 0.0f);    // atomic read: all adds visible
            out[0] = v * (1.0f / (float)NROWS) - 24.0f * (1.0f / 999.0f);
        }
    }
}

extern "C" void kernel_launch(void* const* d_in, const int* in_sizes, int n_in,
                              void* d_out, int out_size, void* d_ws, size_t ws_size,
                              hipStream_t stream)
{
    const float* emb    = (const float*)d_in[0];
    const int*   labels = (const int*)d_in[1];
    float*       out    = (float*)d_out;
    char*        ws     = (char*)d_ws;

    const size_t OFF_CS   = (size_t)NROWS * DIM * 2;            // e: 32 MB
    const size_t OFF_SUMS = OFF_CS + (size_t)CPAD * DIM * 2;    // cs: 512 KB
    const size_t OFF_CNT  = OFF_SUMS + (size_t)CPAD * DIM * 4;  // sums: 1 MB
    const size_t OFF_ACC  = OFF_CNT + (size_t)CPAD * 4;         // counts: 4 KB
    const size_t OFF_DONE = OFF_ACC + 16;

    unsigned short* e      = (unsigned short*)ws;
    unsigned short* cs     = (unsigned short*)(ws + OFF_CS);
    float*          sums   = (float*)(ws + OFF_SUMS);
    unsigned int*   counts = (unsigned int*)(ws + OFF_CNT);
    float*          acc    = (float*)(ws + OFF_ACC);
    unsigned int*   done   = (unsigned int*)(ws + OFF_DONE);

    k_norm_acc      <<<NROWS / 32, 256, 0, stream>>>(emb, e, sums, counts, acc, done);
    k_gather_partial<<<NCLS * 2, 256, 0, stream>>>(e, labels, sums, counts);
    k_centers       <<<CPAD / 4, 256, 0, stream>>>(sums, counts, cs);
    k_loss_mfma     <<<NROWS / TMB, 256, 0, stream>>>(e, cs, labels, acc, done, out);
}